// Round 1
// baseline (382.109 us; speedup 1.0000x reference)
//
#include <hip/hip_runtime.h>

#define S_LEN 2048
#define D_DIM 128
#define NBH   32
#define LOG2E 1.44269504f

typedef __bf16 bf16x8 __attribute__((ext_vector_type(8)));
typedef short  s16x8  __attribute__((ext_vector_type(8)));
typedef float  f32x4  __attribute__((ext_vector_type(4)));

static __device__ __forceinline__ unsigned short f32_to_bf16_bits_exact(float f) {
    // values here are small integers: exactly representable in bf16, truncation is exact
    return (unsigned short)(__float_as_uint(f) >> 16);
}

static __device__ __forceinline__ float round_away(float t) {
    float r = floorf(fabsf(t) + 0.5f);
    return (t >= 0.0f) ? r : -r;
}

// ---------------- per-token quantization of Q and K -----------------
__global__ __launch_bounds__(256) void quant_qk_kernel(
    const float* __restrict__ q, const float* __restrict__ k,
    unsigned short* __restrict__ qq, unsigned short* __restrict__ kq,
    float* __restrict__ qs, float* __restrict__ ks)
{
    const int R = NBH * S_LEN;
    int w    = blockIdx.x * 4 + (threadIdx.x >> 6);
    int lane = threadIdx.x & 63;
    const float* src; unsigned short* dq; float* ds; int row;
    if (w < R) { src = q; dq = qq; ds = qs; row = w; }
    else       { src = k; dq = kq; ds = ks; row = w - R; }
    size_t base = (size_t)row * D_DIM + lane * 2;
    float2 x = *(const float2*)(src + base);
    float amax = fmaxf(fabsf(x.x), fabsf(x.y));
    #pragma unroll
    for (int m = 1; m < 64; m <<= 1) amax = fmaxf(amax, __shfl_xor(amax, m));
    float scale = fmaxf(amax, 1e-8f) / 127.0f;           // matches ref: amax/127 (IEEE div)
    float r0 = fminf(fmaxf(round_away(x.x / scale), -127.0f), 127.0f);
    float r1 = fminf(fmaxf(round_away(x.y / scale), -127.0f), 127.0f);
    ushort2 o; o.x = f32_to_bf16_bits_exact(r0); o.y = f32_to_bf16_bits_exact(r1);
    *(ushort2*)(dq + base) = o;
    if (lane == 0) ds[row] = scale;
}

// ---------------- per-head V amax (deterministic bit-pattern atomicMax) ----
__global__ __launch_bounds__(256) void vamax_kernel(const float* __restrict__ v,
                                                    unsigned int* __restrict__ vab)
{
    int bh = blockIdx.x >> 3, blk = blockIdx.x & 7;
    const float4* base = (const float4*)(v + (size_t)bh * S_LEN * D_DIM) + blk * 8192;
    int t = threadIdx.x;
    float am = 0.0f;
    #pragma unroll
    for (int i = 0; i < 32; ++i) {
        float4 x = base[t + i * 256];
        am = fmaxf(am, fmaxf(fmaxf(fabsf(x.x), fabsf(x.y)), fmaxf(fabsf(x.z), fabsf(x.w))));
    }
    #pragma unroll
    for (int m = 1; m < 64; m <<= 1) am = fmaxf(am, __shfl_xor(am, m));
    __shared__ float red[4];
    if ((t & 63) == 0) red[t >> 6] = am;
    __syncthreads();
    if (t == 0) {
        float a = fmaxf(fmaxf(red[0], red[1]), fmaxf(red[2], red[3]));
        atomicMax(&vab[bh], __float_as_uint(a));   // |v| >= 0: bits compare like floats
    }
}

// ---------------- V quantize + transpose to [B,H,D,S] ----------------------
__global__ __launch_bounds__(256) void vtq_kernel(const float* __restrict__ v,
                                                  const unsigned int* __restrict__ vab,
                                                  unsigned short* __restrict__ vT)
{
    __shared__ unsigned short tileT[128][72];   // padded stride (144B, 16B-mult)
    int bh = blockIdx.x >> 5, sb = blockIdx.x & 31;
    float scale = fmaxf(__uint_as_float(vab[bh]), 1e-8f) / 127.0f;
    int t = threadIdx.x;
    const float* src = v + ((size_t)bh * S_LEN + sb * 64) * D_DIM;
    #pragma unroll
    for (int it = 0; it < 8; ++it) {
        int c = t + it * 256;               // 0..2047 : 64 s-rows x 32 float4
        int rs = c >> 5, c4 = (c & 31) * 4;
        float4 x = *(const float4*)(src + rs * D_DIM + c4);
        float vals[4] = {x.x, x.y, x.z, x.w};
        #pragma unroll
        for (int u = 0; u < 4; ++u) {
            float r = fminf(fmaxf(round_away(vals[u] / scale), -127.0f), 127.0f);
            tileT[c4 + u][rs] = f32_to_bf16_bits_exact(r);
        }
    }
    __syncthreads();
    unsigned short* dst = vT + (size_t)bh * D_DIM * S_LEN + sb * 64;
    #pragma unroll
    for (int it = 0; it < 4; ++it) {
        int c = t + it * 256;               // 0..1023 : 128 d-rows x 8 chunks
        int d = c >> 3, c8 = (c & 7) * 8;
        *(s16x8*)(dst + (size_t)d * S_LEN + c8) = *(const s16x8*)&tileT[d][c8];
    }
}

// ---------------- fused int8 flash attention -------------------------------
__global__ __launch_bounds__(256) void attn_kernel(
    const unsigned short* __restrict__ qq,
    const unsigned short* __restrict__ kq,
    const unsigned short* __restrict__ vT,
    const float* __restrict__ qs,
    const float* __restrict__ ks,
    const unsigned int* __restrict__ vab,
    const float* __restrict__ smp,
    float* __restrict__ out)
{
    __shared__ unsigned short Klds[64][136];   // +8 pad: 272B rows
    __shared__ unsigned short Vlds[128][72];   // V^T tile: [d][key], +8 pad
    __shared__ unsigned short Plds[4][16][72]; // per-wave P transpose tile

    const int tid  = threadIdx.x;
    const int lane = tid & 63;
    const int wid  = tid >> 6;
    const int c16  = lane & 15;
    const int grp  = lane >> 4;

    const int bid = blockIdx.x;
    const int qb  = 31 - (bid & 31);      // long q-blocks dispatched first
    const int bh  = bid >> 5;

    const float qk_scale = smp[0] * LOG2E;
    const float vscale   = fmaxf(__uint_as_float(vab[bh]), 1e-8f) / 127.0f;
    const float vs_term  = vscale / 127.0f;

    const int qrow0 = qb * 64 + wid * 16;

    // Q fragments (A operand): row = c16, k-contiguous 8 per lane
    bf16x8 qfrag[4];
    {
        const unsigned short* qp = qq + ((size_t)bh * S_LEN + qrow0 + c16) * D_DIM + grp * 8;
        #pragma unroll
        for (int ksp = 0; ksp < 4; ++ksp)
            qfrag[ksp] = __builtin_bit_cast(bf16x8, *(const s16x8*)(qp + ksp * 32));
    }
    float qsr[4];
    #pragma unroll
    for (int r = 0; r < 4; ++r) qsr[r] = qs[(size_t)bh * S_LEN + qrow0 + grp * 4 + r];

    float mrow[4], lrow[4];
    f32x4 oacc[8];
    const f32x4 fzero = {0.f, 0.f, 0.f, 0.f};
    #pragma unroll
    for (int r = 0; r < 4; ++r) { mrow[r] = -__builtin_inff(); lrow[r] = 0.0f; }
    #pragma unroll
    for (int d = 0; d < 8; ++d) oacc[d] = fzero;

    for (int j = 0; j <= qb; ++j) {
        __syncthreads();
        {   // stage K tile [64 keys][128 d]
            const unsigned short* gk = kq + ((size_t)bh * S_LEN + j * 64) * D_DIM;
            #pragma unroll
            for (int it = 0; it < 4; ++it) {
                int c = tid + it * 256;
                int r = c >> 4, c8 = (c & 15) * 8;
                *(s16x8*)&Klds[r][c8] = *(const s16x8*)(gk + r * D_DIM + c8);
            }
            // stage V^T tile [128 d][64 keys]
            const unsigned short* gv = vT + (size_t)bh * D_DIM * S_LEN + j * 64;
            #pragma unroll
            for (int it = 0; it < 4; ++it) {
                int c = tid + it * 256;
                int d = c >> 3, c8 = (c & 7) * 8;
                *(s16x8*)&Vlds[d][c8] = *(const s16x8*)(gv + (size_t)d * S_LEN + c8);
            }
        }
        __syncthreads();

        // QK^T: 16 q-rows x 64 keys, exact integer math in bf16 MFMA
        f32x4 sacc[4];
        #pragma unroll
        for (int nt = 0; nt < 4; ++nt) sacc[nt] = fzero;
        #pragma unroll
        for (int ksp = 0; ksp < 4; ++ksp) {
            bf16x8 a = qfrag[ksp];
            #pragma unroll
            for (int nt = 0; nt < 4; ++nt) {
                bf16x8 b = __builtin_bit_cast(bf16x8,
                    *(const s16x8*)&Klds[nt * 16 + c16][ksp * 32 + grp * 8]);
                sacc[nt] = __builtin_amdgcn_mfma_f32_16x16x32_bf16(a, b, sacc[nt], 0, 0, 0);
            }
        }

        // dequant + causal mask (C layout: row = grp*4+reg, col = nt*16+c16)
        float sq[4][4];
        #pragma unroll
        for (int nt = 0; nt < 4; ++nt) {
            float ksv = ks[(size_t)bh * S_LEN + j * 64 + nt * 16 + c16];
            #pragma unroll
            for (int r = 0; r < 4; ++r) {
                float val = ((sacc[nt][r] * qsr[r]) * ksv) * qk_scale;
                int rg = qrow0 + grp * 4 + r;
                int cg = j * 64 + nt * 16 + c16;
                sq[nt][r] = (rg >= cg) ? val : -1000000.0f;
            }
        }

        // online softmax (base-2), row owned by 16 lanes of same grp
        float mnew[4], alpha[4];
        #pragma unroll
        for (int r = 0; r < 4; ++r) {
            float vm = fmaxf(fmaxf(sq[0][r], sq[1][r]), fmaxf(sq[2][r], sq[3][r]));
            #pragma unroll
            for (int m = 1; m < 16; m <<= 1) vm = fmaxf(vm, __shfl_xor(vm, m));
            mnew[r] = fmaxf(mrow[r], vm);
            alpha[r] = exp2f(mrow[r] - mnew[r]);
            mrow[r] = mnew[r];
        }
        float p[4][4];
        float psum[4] = {0.f, 0.f, 0.f, 0.f};
        #pragma unroll
        for (int nt = 0; nt < 4; ++nt)
            #pragma unroll
            for (int r = 0; r < 4; ++r) {
                float pv = exp2f(sq[nt][r] - mnew[r]);
                p[nt][r] = pv;
                psum[r] += pv;
            }
        #pragma unroll
        for (int r = 0; r < 4; ++r) {
            float s = psum[r];
            #pragma unroll
            for (int m = 1; m < 16; m <<= 1) s += __shfl_xor(s, m);
            lrow[r] = lrow[r] * alpha[r] + s;
        }

        // quantized P -> per-wave LDS tile (transpose for A-operand)
        #pragma unroll
        for (int nt = 0; nt < 4; ++nt)
            #pragma unroll
            for (int r = 0; r < 4; ++r) {
                float pqv = floorf(p[nt][r] * 127.0f + 0.5f);
                Plds[wid][grp * 4 + r][nt * 16 + c16] = f32_to_bf16_bits_exact(pqv);
            }

        // rescale accumulator by alpha (same order as reference)
        #pragma unroll
        for (int d = 0; d < 8; ++d)
            #pragma unroll
            for (int r = 0; r < 4; ++r) oacc[d][r] *= alpha[r];

        // PV: accumulate raw-integer p_q @ v_q (vs_term deferred to epilogue)
        #pragma unroll
        for (int k2 = 0; k2 < 2; ++k2) {
            bf16x8 pa = __builtin_bit_cast(bf16x8,
                *(const s16x8*)&Plds[wid][c16][k2 * 32 + grp * 8]);
            #pragma unroll
            for (int dt = 0; dt < 8; ++dt) {
                bf16x8 b = __builtin_bit_cast(bf16x8,
                    *(const s16x8*)&Vlds[dt * 16 + c16][k2 * 32 + grp * 8]);
                oacc[dt] = __builtin_amdgcn_mfma_f32_16x16x32_bf16(pa, b, oacc[dt], 0, 0, 0);
            }
        }
    }

    // epilogue: out = (acc_int * vs_term) / l
    #pragma unroll
    for (int dt = 0; dt < 8; ++dt) {
        #pragma unroll
        for (int r = 0; r < 4; ++r) {
            int rg = qrow0 + grp * 4 + r;
            out[((size_t)bh * S_LEN + rg) * D_DIM + dt * 16 + c16] =
                (oacc[dt][r] * vs_term) / lrow[r];
        }
    }
}

extern "C" void kernel_launch(void* const* d_in, const int* in_sizes, int n_in,
                              void* d_out, int out_size, void* d_ws, size_t ws_size,
                              hipStream_t stream)
{
    const float* q  = (const float*)d_in[0];
    const float* k  = (const float*)d_in[1];
    const float* v  = (const float*)d_in[2];
    const float* sm = (const float*)d_in[3];

    // workspace layout (bytes): qq 16MB | kq 16MB | vT 16MB | qs 256KB | ks 256KB | vab 128B
    if (ws_size < (size_t)50857000) return;   // would show as all-zero output
    char* ws = (char*)d_ws;
    unsigned short* qq = (unsigned short*)(ws);
    unsigned short* kq = (unsigned short*)(ws + (1u << 24));
    unsigned short* vT = (unsigned short*)(ws + (2u << 24));
    float*          qs = (float*)(ws + (3u << 24));
    float*          ks = (float*)(ws + (3u << 24) + 262144);
    unsigned int*  vab = (unsigned int*)(ws + (3u << 24) + 524288);
    float*         out = (float*)d_out;

    hipMemsetAsync(vab, 0, NBH * sizeof(unsigned int), stream);
    quant_qk_kernel<<<dim3(32768), dim3(256), 0, stream>>>(q, k, qq, kq, qs, ks);
    vamax_kernel<<<dim3(256), dim3(256), 0, stream>>>(v, vab);
    vtq_kernel<<<dim3(1024), dim3(256), 0, stream>>>(v, vab, vT);
    attn_kernel<<<dim3(1024), dim3(256), 0, stream>>>(qq, kq, vT, qs, ks, vab, sm, out);
}

// Round 2
// 150.312 us; speedup vs baseline: 2.5421x; 2.5421x over previous
//
#include <hip/hip_runtime.h>

#define S_LEN 2048
#define D_DIM 128
#define NBH   32
#define LOG2E 1.44269504f
#define NEGM  -1000000.0f

typedef __bf16 bf16x8 __attribute__((ext_vector_type(8)));
typedef short  s16x8  __attribute__((ext_vector_type(8)));
typedef float  f32x4  __attribute__((ext_vector_type(4)));
typedef float  f32x16 __attribute__((ext_vector_type(16)));
typedef unsigned int u32x4 __attribute__((ext_vector_type(4)));

static __device__ __forceinline__ unsigned short f32_to_bf16_bits_exact(float f) {
    return (unsigned short)(__float_as_uint(f) >> 16);   // exact for small ints
}
static __device__ __forceinline__ unsigned int pack_bf16(float lo, float hi) {
    return (__float_as_uint(lo) >> 16) | (__float_as_uint(hi) & 0xffff0000u);
}
static __device__ __forceinline__ float round_away(float t) {
    float r = floorf(fabsf(t) + 0.5f);
    return (t >= 0.0f) ? r : -r;
}

// ---------------- per-token quantization of Q and K -----------------
__global__ __launch_bounds__(256) void quant_qk_kernel(
    const float* __restrict__ q, const float* __restrict__ k,
    unsigned short* __restrict__ qq, unsigned short* __restrict__ kq,
    float* __restrict__ qs, float* __restrict__ ks)
{
    const int R = NBH * S_LEN;
    int w    = blockIdx.x * 4 + (threadIdx.x >> 6);
    int lane = threadIdx.x & 63;
    const float* src; unsigned short* dq; float* ds; int row;
    if (w < R) { src = q; dq = qq; ds = qs; row = w; }
    else       { src = k; dq = kq; ds = ks; row = w - R; }
    size_t base = (size_t)row * D_DIM + lane * 2;
    float2 x = *(const float2*)(src + base);
    float amax = fmaxf(fabsf(x.x), fabsf(x.y));
    #pragma unroll
    for (int m = 1; m < 64; m <<= 1) amax = fmaxf(amax, __shfl_xor(amax, m));
    float scale = fmaxf(amax, 1e-8f) / 127.0f;
    float r0 = fminf(fmaxf(round_away(x.x / scale), -127.0f), 127.0f);
    float r1 = fminf(fmaxf(round_away(x.y / scale), -127.0f), 127.0f);
    ushort2 o; o.x = f32_to_bf16_bits_exact(r0); o.y = f32_to_bf16_bits_exact(r1);
    *(ushort2*)(dq + base) = o;
    if (lane == 0) ds[row] = scale;
}

// ---------------- per-head V amax (deterministic bit-pattern atomicMax) ----
__global__ __launch_bounds__(256) void vamax_kernel(const float* __restrict__ v,
                                                    unsigned int* __restrict__ vab)
{
    int bh = blockIdx.x >> 3, blk = blockIdx.x & 7;
    const float4* base = (const float4*)(v + (size_t)bh * S_LEN * D_DIM) + blk * 8192;
    int t = threadIdx.x;
    float am = 0.0f;
    #pragma unroll
    for (int i = 0; i < 32; ++i) {
        float4 x = base[t + i * 256];
        am = fmaxf(am, fmaxf(fmaxf(fabsf(x.x), fabsf(x.y)), fmaxf(fabsf(x.z), fabsf(x.w))));
    }
    #pragma unroll
    for (int m = 1; m < 64; m <<= 1) am = fmaxf(am, __shfl_xor(am, m));
    __shared__ float red[4];
    if ((t & 63) == 0) red[t >> 6] = am;
    __syncthreads();
    if (t == 0) {
        float a = fmaxf(fmaxf(red[0], red[1]), fmaxf(red[2], red[3]));
        atomicMax(&vab[bh], __float_as_uint(a));
    }
}

// ---------------- V quantize + transpose to [B,H,D,S] ----------------------
__global__ __launch_bounds__(256) void vtq_kernel(const float* __restrict__ v,
                                                  const unsigned int* __restrict__ vab,
                                                  unsigned short* __restrict__ vT)
{
    __shared__ unsigned short tileT[128][72];
    int bh = blockIdx.x >> 5, sb = blockIdx.x & 31;
    float scale = fmaxf(__uint_as_float(vab[bh]), 1e-8f) / 127.0f;
    int t = threadIdx.x;
    const float* src = v + ((size_t)bh * S_LEN + sb * 64) * D_DIM;
    #pragma unroll
    for (int it = 0; it < 8; ++it) {
        int c = t + it * 256;
        int rs = c >> 5, c4 = (c & 31) * 4;
        float4 x = *(const float4*)(src + rs * D_DIM + c4);
        float vals[4] = {x.x, x.y, x.z, x.w};
        #pragma unroll
        for (int u = 0; u < 4; ++u) {
            float r = fminf(fmaxf(round_away(vals[u] / scale), -127.0f), 127.0f);
            tileT[c4 + u][rs] = f32_to_bf16_bits_exact(r);
        }
    }
    __syncthreads();
    unsigned short* dst = vT + (size_t)bh * D_DIM * S_LEN + sb * 64;
    #pragma unroll
    for (int it = 0; it < 4; ++it) {
        int c = t + it * 256;
        int d = c >> 3, c8 = (c & 7) * 8;
        *(s16x8*)(dst + (size_t)d * S_LEN + c8) = *(const s16x8*)&tileT[d][c8];
    }
}

// ---------------- fused int8 flash attention (swapped 32x32 MFMA) ----------
__global__ __launch_bounds__(256) void attn_kernel(
    const unsigned short* __restrict__ qq,
    const unsigned short* __restrict__ kq,
    const unsigned short* __restrict__ vT,
    const float* __restrict__ qs,
    const float* __restrict__ ks,
    const unsigned int* __restrict__ vab,
    const float* __restrict__ smp,
    float* __restrict__ out)
{
    extern __shared__ char smem[];
    char*  Kb  = smem;                    // 16 KB: K tile, rows 256B, XOR-swizzled
    char*  Vb  = smem + 16384;            // 16 KB: V^T packed [32 rho][512B], XOR-swizzled
    float* ksl = (float*)(smem + 32768);  //  8 KB: full ks row of this head
    float* Ol  = (float*)smem;            // epilogue union: 2 x [32][132] f32

    const int tid  = threadIdx.x;
    const int lane = tid & 63;
    const int wid  = tid >> 6;
    const int c32  = lane & 31;
    const int hi   = lane >> 5;

    const int bid = blockIdx.x;
    const int qb  = 15 - (bid >> 5);      // long WGs dispatched first (LPT)
    const int bh  = bid & 31;

    const float qk_scale = smp[0] * LOG2E;
    const float vscale   = fmaxf(__uint_as_float(vab[bh]), 1e-8f) / 127.0f;
    const float vs_term  = vscale / 127.0f;

    const int   q  = qb * 128 + c32 * 4 + wid;   // this lane's q row (strided over waves)
    const float qf = qs[(size_t)bh * S_LEN + q] * qk_scale;

    {   // stage full ks row (8 KB) once
        const f32x4* src = (const f32x4*)(ks + (size_t)bh * S_LEN);
        f32x4* dst = (f32x4*)ksl;
        dst[tid]       = src[tid];
        dst[tid + 256] = src[tid + 256];
    }

    // Q fragments: lane holds its q-row; frag st covers d = st*16 + hi*8 .. +7
    bf16x8 qfrag[8];
    {
        const char* qrow = (const char*)(qq + ((size_t)bh * S_LEN + q) * D_DIM);
        #pragma unroll
        for (int st = 0; st < 8; ++st)
            qfrag[st] = __builtin_bit_cast(bf16x8, *(const s16x8*)(qrow + st * 32 + hi * 16));
    }

    float mrow = -__builtin_inff();
    float lrow = 0.0f;
    f32x16 oacc0, oacc1, oacc2, oacc3;
    #pragma unroll
    for (int i = 0; i < 16; ++i) { oacc0[i] = 0.f; oacc1[i] = 0.f; oacc2[i] = 0.f; oacc3[i] = 0.f; }

    const char* kqb = (const char*)(kq + (size_t)bh * S_LEN * D_DIM);
    const char* vtb = (const char*)(vT + (size_t)bh * D_DIM * S_LEN);

    const int jend = 2 * qb + 1;
    for (int j = 0; j <= jend; ++j) {
        const int jb = j * 64;
        __syncthreads();
        // stage K tile: LDS[r][x] = K[jb+r][x ^ ((r&15)<<4)]  (rows 256B, linear dest)
        #pragma unroll
        for (int it = 0; it < 4; ++it) {
            int L = (tid + it * 256) * 16;
            int r = L >> 8;
            int x = L & 255;
            int c = x ^ ((r & 15) << 4);
            *(s16x8*)(Kb + L) = *(const s16x8*)(kqb + (size_t)(jb + r) * 256 + c);
        }
        // stage V^T packed: row rho=d%32 (512B: 4 d-tiles x 64 keys), XOR-swizzled
        #pragma unroll
        for (int it = 0; it < 4; ++it) {
            int L   = (tid + it * 256) * 16;
            int rho = L >> 9;
            int x   = L & 511;
            int c   = x ^ ((rho & 15) << 4);
            int d   = (c >> 7) * 32 + rho;
            *(s16x8*)(Vb + L) = *(const s16x8*)(vtb + (size_t)d * (S_LEN * 2) + jb * 2 + (c & 127));
        }
        __syncthreads();

        // ---- swapped QK^T: S^T = K · Q^T, two 32-key tiles ----
        f32x16 sc0, sc1;
        #pragma unroll
        for (int i = 0; i < 16; ++i) { sc0[i] = 0.f; sc1[i] = 0.f; }
        {
            const int swz = (c32 & 15) << 4;
            #pragma unroll
            for (int st = 0; st < 8; ++st) {
                int cB = st * 32 + hi * 16;
                bf16x8 a0 = __builtin_bit_cast(bf16x8, *(const s16x8*)(Kb + c32 * 256        + (cB ^ swz)));
                bf16x8 a1 = __builtin_bit_cast(bf16x8, *(const s16x8*)(Kb + (c32 + 32) * 256 + (cB ^ swz)));
                sc0 = __builtin_amdgcn_mfma_f32_32x32x16_bf16(a0, qfrag[st], sc0, 0, 0, 0);
                sc1 = __builtin_amdgcn_mfma_f32_32x32x16_bf16(a1, qfrag[st], sc1, 0, 0, 0);
            }
        }

        // ---- dequant + causal mask + row max (all lane-local; key=(r&3)+8*(r>>2)+4*hi) ----
        const bool need_mask = (jb + 63 > qb * 128 + wid);
        float s0[16], s1[16];
        float mh = -__builtin_inff();
        #pragma unroll
        for (int g = 0; g < 4; ++g) {
            f32x4 kv0 = *(const f32x4*)&ksl[jb + g * 8 + hi * 4];
            f32x4 kv1 = *(const f32x4*)&ksl[jb + 32 + g * 8 + hi * 4];
            #pragma unroll
            for (int i = 0; i < 4; ++i) {
                int r = g * 4 + i;
                float v0 = sc0[r] * qf * kv0[i];
                float v1 = sc1[r] * qf * kv1[i];
                if (need_mask) {
                    int key0 = jb + g * 8 + i + hi * 4;
                    v0 = (q >= key0)      ? v0 : NEGM;
                    v1 = (q >= key0 + 32) ? v1 : NEGM;
                }
                s0[r] = v0; s1[r] = v1;
                mh = fmaxf(mh, fmaxf(v0, v1));
            }
        }
        float vmax  = fmaxf(mh, __shfl_xor(mh, 32));
        float mnew  = fmaxf(mrow, vmax);
        float alpha = exp2f(mrow - mnew);
        mrow = mnew;

        float psum = 0.0f;
        #pragma unroll
        for (int r = 0; r < 16; ++r) {
            s0[r] = exp2f(s0[r] - mnew);
            s1[r] = exp2f(s1[r] - mnew);
            psum += s0[r] + s1[r];
        }
        psum += __shfl_xor(psum, 32);
        lrow = lrow * alpha + psum;

        // ---- p_q -> packed bf16 words + cross-half exchange ----
        unsigned int W0[8], W1[8], X0[8], X1[8];
        #pragma unroll
        for (int g = 0; g < 4; ++g) {
            float a0 = floorf(s0[g*4+0] * 127.0f + 0.5f);
            float a1 = floorf(s0[g*4+1] * 127.0f + 0.5f);
            float a2 = floorf(s0[g*4+2] * 127.0f + 0.5f);
            float a3 = floorf(s0[g*4+3] * 127.0f + 0.5f);
            W0[g*2+0] = pack_bf16(a0, a1);
            W0[g*2+1] = pack_bf16(a2, a3);
            float b0 = floorf(s1[g*4+0] * 127.0f + 0.5f);
            float b1 = floorf(s1[g*4+1] * 127.0f + 0.5f);
            float b2 = floorf(s1[g*4+2] * 127.0f + 0.5f);
            float b3 = floorf(s1[g*4+3] * 127.0f + 0.5f);
            W1[g*2+0] = pack_bf16(b0, b1);
            W1[g*2+1] = pack_bf16(b2, b3);
        }
        #pragma unroll
        for (int i = 0; i < 8; ++i) {
            X0[i] = (unsigned int)__shfl_xor((int)W0[i], 32);
            X1[i] = (unsigned int)__shfl_xor((int)W1[i], 32);
        }

        // ---- rescale O^T by alpha (lane-uniform scalar) ----
        #pragma unroll
        for (int i = 0; i < 16; ++i) {
            oacc0[i] *= alpha; oacc1[i] *= alpha; oacc2[i] *= alpha; oacc3[i] *= alpha;
        }

        // ---- PV: O^T += V^T · P^T ----
        const int vswz = (c32 & 15) << 4;
        #pragma unroll
        for (int t = 0; t < 2; ++t) {
            #pragma unroll
            for (int s = 0; s < 2; ++s) {
                unsigned int w0, w1, w2, w3;
                if (t == 0) {
                    w0 = hi ? X0[s*4+2] : W0[s*4+0];
                    w1 = hi ? X0[s*4+3] : W0[s*4+1];
                    w2 = hi ? W0[s*4+2] : X0[s*4+0];
                    w3 = hi ? W0[s*4+3] : X0[s*4+1];
                } else {
                    w0 = hi ? X1[s*4+2] : W1[s*4+0];
                    w1 = hi ? X1[s*4+3] : W1[s*4+1];
                    w2 = hi ? W1[s*4+2] : X1[s*4+0];
                    w3 = hi ? W1[s*4+3] : X1[s*4+1];
                }
                u32x4 uw; uw.x = w0; uw.y = w1; uw.z = w2; uw.w = w3;
                bf16x8 bfrag = __builtin_bit_cast(bf16x8, uw);
                int cb = t * 64 + s * 32 + hi * 16;
                bf16x8 va;
                va = __builtin_bit_cast(bf16x8, *(const s16x8*)(Vb + c32 * 512 + ((cb +   0) ^ vswz)));
                oacc0 = __builtin_amdgcn_mfma_f32_32x32x16_bf16(va, bfrag, oacc0, 0, 0, 0);
                va = __builtin_bit_cast(bf16x8, *(const s16x8*)(Vb + c32 * 512 + ((cb + 128) ^ vswz)));
                oacc1 = __builtin_amdgcn_mfma_f32_32x32x16_bf16(va, bfrag, oacc1, 0, 0, 0);
                va = __builtin_bit_cast(bf16x8, *(const s16x8*)(Vb + c32 * 512 + ((cb + 256) ^ vswz)));
                oacc2 = __builtin_amdgcn_mfma_f32_32x32x16_bf16(va, bfrag, oacc2, 0, 0, 0);
                va = __builtin_bit_cast(bf16x8, *(const s16x8*)(Vb + c32 * 512 + ((cb + 384) ^ vswz)));
                oacc3 = __builtin_amdgcn_mfma_f32_32x32x16_bf16(va, bfrag, oacc3, 0, 0, 0);
            }
        }
    }

    // ---- epilogue: O^T -> LDS transpose -> coalesced stores (2 passes) ----
    for (int pass = 0; pass < 2; ++pass) {
        __syncthreads();
        if ((wid >> 1) == pass) {
            float* reg = Ol + (wid & 1) * 4224 + c32 * 132;
            #pragma unroll
            for (int r = 0; r < 16; ++r) {
                int drow = (r & 3) + 8 * (r >> 2) + 4 * hi;
                reg[drow]      = (oacc0[r] * vs_term) / lrow;
                reg[drow + 32] = (oacc1[r] * vs_term) / lrow;
                reg[drow + 64] = (oacc2[r] * vs_term) / lrow;
                reg[drow + 96] = (oacc3[r] * vs_term) / lrow;
            }
        }
        __syncthreads();
        #pragma unroll
        for (int it = 0; it < 8; ++it) {
            int idx = tid + it * 256;
            int w2  = idx >> 10;
            int rem = idx & 1023;
            int row = rem >> 5, c4 = rem & 31;
            f32x4 v4 = *(const f32x4*)(Ol + w2 * 4224 + row * 132 + c4 * 4);
            int qr = qb * 128 + row * 4 + pass * 2 + w2;
            *(f32x4*)(out + ((size_t)bh * S_LEN + qr) * D_DIM + c4 * 4) = v4;
        }
    }
}

extern "C" void kernel_launch(void* const* d_in, const int* in_sizes, int n_in,
                              void* d_out, int out_size, void* d_ws, size_t ws_size,
                              hipStream_t stream)
{
    const float* q  = (const float*)d_in[0];
    const float* k  = (const float*)d_in[1];
    const float* v  = (const float*)d_in[2];
    const float* sm = (const float*)d_in[3];

    if (ws_size < (size_t)50857000) return;
    char* ws = (char*)d_ws;
    unsigned short* qq = (unsigned short*)(ws);
    unsigned short* kq = (unsigned short*)(ws + (1u << 24));
    unsigned short* vT = (unsigned short*)(ws + (2u << 24));
    float*          qs = (float*)(ws + (3u << 24));
    float*          ks = (float*)(ws + (3u << 24) + 262144);
    unsigned int*  vab = (unsigned int*)(ws + (3u << 24) + 524288);
    float*         out = (float*)d_out;

    hipMemsetAsync(vab, 0, NBH * sizeof(unsigned int), stream);
    quant_qk_kernel<<<dim3(32768), dim3(256), 0, stream>>>(q, k, qq, kq, qs, ks);
    vamax_kernel<<<dim3(256), dim3(256), 0, stream>>>(v, vab);
    vtq_kernel<<<dim3(1024), dim3(256), 0, stream>>>(v, vab, vT);
    attn_kernel<<<dim3(512), dim3(256), 40960, stream>>>(qq, kq, vT, qs, ks, vab, sm, out);
}